// Round 3
// baseline (15907.283 us; speedup 1.0000x reference)
//
#include <hip/hip_runtime.h>
#include <math.h>

// DCGRU encoder, fused persistent kernel, fp32, manual grid barrier.
// B=16 T=32 N=128 D=H=128, K=2 (M=3), L=2, 1 support.
// Grid: 256 blocks x 256 threads (<=1 per CU guaranteed resident).

namespace {
constexpr int Tn = 32, Nn = 128, Dn = 128, Hn = 128;
constexpr int CATF = 256, K3 = 768, OG = 256, OC = 128, ROWS = 2048;
constexpr int GD = 256, NTHR = 256;
}

// sense-reversing grid barrier; bar[0]=count, bar[32]=generation
__device__ __forceinline__ void grid_barrier(unsigned* bar) {
  __syncthreads();
  if (threadIdx.x == 0) {
    unsigned* cnt = bar;
    unsigned* gen = bar + 32;
    unsigned g = __hip_atomic_load(gen, __ATOMIC_RELAXED, __HIP_MEMORY_SCOPE_AGENT);
    unsigned a = __hip_atomic_fetch_add(cnt, 1u, __ATOMIC_ACQ_REL, __HIP_MEMORY_SCOPE_AGENT);
    if (a == (unsigned)(GD - 1)) {
      __hip_atomic_store(cnt, 0u, __ATOMIC_RELAXED, __HIP_MEMORY_SCOPE_AGENT);
      __hip_atomic_fetch_add(gen, 1u, __ATOMIC_ACQ_REL, __HIP_MEMORY_SCOPE_AGENT);
    } else {
      while (__hip_atomic_load(gen, __ATOMIC_ACQUIRE, __HIP_MEMORY_SCOPE_AGENT) == g) {
        __builtin_amdgcn_s_sleep(1);
      }
    }
  }
  __syncthreads();
}

// D1 = S @ cat, D2 = 2 S @ D1 - cat for one (batch, 16-feature tile).
// lds: Sl[64][129] | catb[128][16] | tmpb[128][16]
__device__ __forceinline__ void diffusion_phase(
    int bid, int tid, const float* __restrict__ S,
    const float* __restrict__ xbase, long xbs, const float* __restrict__ hsrc,
    float* __restrict__ D1g, float* __restrict__ D2g, float* lds) {
  float* Sl   = lds;                 // 64*129
  float* catb = lds + 64 * 129;      // 128*16
  float* tmpb = catb + 128 * 16;     // 128*16
  const int b  = bid >> 4;
  const int f0 = (bid & 15) * 16;

  for (int i = tid; i < Nn * 16; i += NTHR) {
    const int n = i >> 4, c = i & 15, f = f0 + c;
    catb[i] = (f < Dn) ? xbase[(long)b * xbs + n * Dn + f]
                       : hsrc[(((b << 7) + n) << 7) + (f - Dn)];
  }
  const int cc = (tid & 7) * 2;   // col pair within 16-feature tile
  const int gg = tid >> 3;        // 0..31 -> row pair within 64-row half

  for (int pass = 0; pass < 2; pass++) {
    const float* src = pass ? tmpb : catb;
    for (int h0 = 0; h0 < 128; h0 += 64) {
      __syncthreads();  // protect Sl overwrite + catb/tmpb readiness
      for (int i = tid; i < 64 * 32; i += NTHR) {
        const int r = i >> 5, nq = (i & 31) * 4;
        const float4 sv = *(const float4*)&S[(h0 + r) * 128 + nq];
        float* dst = &Sl[r * 129 + nq];
        dst[0] = sv.x; dst[1] = sv.y; dst[2] = sv.z; dst[3] = sv.w;
      }
      __syncthreads();
      const int r0 = gg * 2;
      float a00 = 0.f, a01 = 0.f, a10 = 0.f, a11 = 0.f;
#pragma unroll 4
      for (int n = 0; n < 128; n++) {
        const float s0 = Sl[r0 * 129 + n];
        const float s1 = Sl[(r0 + 1) * 129 + n];
        const float2 v = *(const float2*)&src[n * 16 + cc];
        a00 += s0 * v.x; a01 += s0 * v.y;
        a10 += s1 * v.x; a11 += s1 * v.y;
      }
      const int m0 = h0 + r0;                 // node row
      const long grow0 = ((long)(b << 7) + m0) << 8;
      if (pass == 0) {
        tmpb[m0 * 16 + cc] = a00; tmpb[m0 * 16 + cc + 1] = a01;
        tmpb[(m0 + 1) * 16 + cc] = a10; tmpb[(m0 + 1) * 16 + cc + 1] = a11;
        *(float2*)&D1g[grow0 + f0 + cc] = make_float2(a00, a01);
        *(float2*)&D1g[grow0 + 256 + f0 + cc] = make_float2(a10, a11);
      } else {
        const float c00 = catb[m0 * 16 + cc], c01 = catb[m0 * 16 + cc + 1];
        const float c10 = catb[(m0 + 1) * 16 + cc], c11 = catb[(m0 + 1) * 16 + cc + 1];
        *(float2*)&D2g[grow0 + f0 + cc] = make_float2(2.f * a00 - c00, 2.f * a01 - c01);
        *(float2*)&D2g[grow0 + 256 + f0 + cc] = make_float2(2.f * a10 - c10, 2.f * a11 - c11);
      }
    }
  }
}

__global__ void __launch_bounds__(NTHR) dcgru_fused(
    const float* __restrict__ inputs, const float* __restrict__ init_h,
    const float* __restrict__ sup,
    const float* __restrict__ Wg0, const float* __restrict__ bg0,
    const float* __restrict__ Wc0, const float* __restrict__ bc0,
    const float* __restrict__ Wg1, const float* __restrict__ bg1,
    const float* __restrict__ Wc1, const float* __restrict__ bc1,
    float* __restrict__ out, float* __restrict__ ws) {
  __shared__ float LDSU[64 * 129 + 2 * 128 * 16];  // 12544 floats = 50176 B

  unsigned* bar = (unsigned*)ws;
  float* base = ws + 64;
  float* Wgr  = base;
  float* Wcr  = Wgr + 2 * K3 * OG;
  float* h    = Wcr + 2 * K3 * OC;
  float* D1   = h + ROWS * Hn;
  float* D2   = D1 + ROWS * CATF;
  float* rh   = D2 + ROWS * CATF;
  float* uu   = rh + ROWS * Hn;
  float* seq0 = uu + ROWS * Hn;

  const int tid = threadIdx.x;
  const int bid = blockIdx.x;
  const int gtid = bid * NTHR + tid;
  const int gstride = GD * NTHR;

  // weight rearrange: rows (d*3+m) -> (m*256+d)
  for (int idx = gtid; idx < 2 * K3 * OG; idx += gstride) {
    const int l = idx / (K3 * OG);
    const int rem = idx - l * (K3 * OG);
    const int r = rem / OG, o = rem - r * OG;
    const int m = r / CATF, d = r - m * CATF;
    const float* W = l ? Wg1 : Wg0;
    Wgr[idx] = W[(d * 3 + m) * OG + o];
  }
  for (int idx = gtid; idx < 2 * K3 * OC; idx += gstride) {
    const int l = idx / (K3 * OC);
    const int rem = idx - l * (K3 * OC);
    const int r = rem / OC, o = rem - r * OC;
    const int m = r / CATF, d = r - m * CATF;
    const float* W = l ? Wc1 : Wc0;
    Wcr[idx] = W[(d * 3 + m) * OC + o];
  }
  grid_barrier(bar);

  for (int l = 0; l < 2; l++) {
    const float* Wgl = Wgr + l * K3 * OG;
    const float* Wcl = Wcr + l * K3 * OC;
    const float* bgl = l ? bg1 : bg0;
    const float* bcl = l ? bc1 : bc0;
    for (int i = gtid; i < ROWS * Hn; i += gstride)
      h[i] = init_h[l * ROWS * Hn + i];
    grid_barrier(bar);

    for (int t = 0; t < Tn; t++) {
      const float* S = sup + (long)t * Nn * Nn;
      const float* xbase = (l == 0) ? inputs + (long)t * Nn * Dn
                                    : seq0 + (long)t * ROWS * Hn;
      const long xbs = (l == 0) ? (long)Tn * Nn * Dn : (long)Nn * Hn;

      // P1: diffusion on h
      diffusion_phase(bid, tid, S, xbase, xbs, h, D1, D2, LDSU);
      grid_barrier(bar);

      // P2: gates; block = 16 rows x 128-out half
      {
        float* Buf = LDSU;  // [16][768]
        const int row0 = (bid >> 1) * 16;
        const int ob   = (bid & 1) * 128;
        for (int i = tid; i < 16 * K3; i += NTHR) {
          const int rr = i / K3, k = i - rr * K3;
          const int row = row0 + rr, b = row >> 7, n = row & 127;
          float v;
          if (k < Dn)        v = xbase[(long)b * xbs + n * Dn + k];
          else if (k < CATF) v = h[(row << 7) + (k - Dn)];
          else if (k < 512)  v = D1[(row << 8) + (k - CATF)];
          else               v = D2[(row << 8) + (k - 512)];
          Buf[i] = v;
        }
        __syncthreads();
        const int o2 = ob + (tid & 63) * 2;
        const int r0 = (tid >> 6) * 4;   // wave-uniform
        float acc[4][2] = {};
        const float* Wp = Wgl + o2;
        for (int k = 0; k < K3; k += 4) {
          const float2 w0 = *(const float2*)&Wp[(k + 0) << 8];
          const float2 w1 = *(const float2*)&Wp[(k + 1) << 8];
          const float2 w2 = *(const float2*)&Wp[(k + 2) << 8];
          const float2 w3 = *(const float2*)&Wp[(k + 3) << 8];
#pragma unroll
          for (int i = 0; i < 4; i++) {
            const float4 x = *(const float4*)&Buf[(r0 + i) * K3 + k];
            acc[i][0] += x.x * w0.x + x.y * w1.x + x.z * w2.x + x.w * w3.x;
            acc[i][1] += x.x * w0.y + x.y * w1.y + x.z * w2.y + x.w * w3.y;
          }
        }
        const float b0 = bgl[o2], b1 = bgl[o2 + 1];
#pragma unroll
        for (int i = 0; i < 4; i++) {
          const int row = row0 + r0 + i;
          const float g0 = 1.f / (1.f + __expf(-(acc[i][0] + b0)));
          const float g1 = 1.f / (1.f + __expf(-(acc[i][1] + b1)));
          if (ob == 0) {
            const float2 hv = *(const float2*)&h[(row << 7) + o2];
            *(float2*)&rh[(row << 7) + o2] = make_float2(g0 * hv.x, g1 * hv.y);
          } else {
            *(float2*)&uu[(row << 7) + (o2 - 128)] = make_float2(g0, g1);
          }
        }
      }
      grid_barrier(bar);

      // P3: diffusion on rh
      diffusion_phase(bid, tid, S, xbase, xbs, rh, D1, D2, LDSU);
      grid_barrier(bar);

      // P4: candidate + update; block = 8 rows x 128 outs
      {
        float* Buf = LDSU;  // [8][768]
        const int row0 = bid * 8;
        for (int i = tid; i < 8 * K3; i += NTHR) {
          const int rr = i / K3, k = i - rr * K3;
          const int row = row0 + rr, b = row >> 7, n = row & 127;
          float v;
          if (k < Dn)        v = xbase[(long)b * xbs + n * Dn + k];
          else if (k < CATF) v = rh[(row << 7) + (k - Dn)];
          else if (k < 512)  v = D1[(row << 8) + (k - CATF)];
          else               v = D2[(row << 8) + (k - 512)];
          Buf[i] = v;
        }
        __syncthreads();
        const int o2 = (tid & 63) * 2;
        const int r0 = (tid >> 6) * 2;   // wave-uniform
        float acc[2][2] = {};
        const float* Wp = Wcl + o2;
        for (int k = 0; k < K3; k += 4) {
          const float2 w0 = *(const float2*)&Wp[(k + 0) << 7];
          const float2 w1 = *(const float2*)&Wp[(k + 1) << 7];
          const float2 w2 = *(const float2*)&Wp[(k + 2) << 7];
          const float2 w3 = *(const float2*)&Wp[(k + 3) << 7];
#pragma unroll
          for (int i = 0; i < 2; i++) {
            const float4 x = *(const float4*)&Buf[(r0 + i) * K3 + k];
            acc[i][0] += x.x * w0.x + x.y * w1.x + x.z * w2.x + x.w * w3.x;
            acc[i][1] += x.x * w0.y + x.y * w1.y + x.z * w2.y + x.w * w3.y;
          }
        }
        float* seq_out = (l == 0) ? seq0 + (long)t * ROWS * Hn
                                  : out + (long)2 * ROWS * Hn + (long)t * ROWS * Hn;
        float* finals_out = (t == Tn - 1) ? out + (long)l * ROWS * Hn : nullptr;
        const float b0 = bcl[o2], b1 = bcl[o2 + 1];
#pragma unroll
        for (int i = 0; i < 2; i++) {
          const int row = row0 + r0 + i;
          const float c0 = tanhf(acc[i][0] + b0);
          const float c1 = tanhf(acc[i][1] + b1);
          const float2 uv = *(const float2*)&uu[(row << 7) + o2];
          const float2 hv = *(const float2*)&h[(row << 7) + o2];
          const float hn0 = uv.x * hv.x + (1.f - uv.x) * c0;
          const float hn1 = uv.y * hv.y + (1.f - uv.y) * c1;
          *(float2*)&h[(row << 7) + o2] = make_float2(hn0, hn1);
          *(float2*)&seq_out[(row << 7) + o2] = make_float2(hn0, hn1);
          if (finals_out)
            *(float2*)&finals_out[(row << 7) + o2] = make_float2(hn0, hn1);
        }
      }
      grid_barrier(bar);
    }
  }
}

extern "C" void kernel_launch(void* const* d_in, const int* in_sizes, int n_in,
                              void* d_out, int out_size, void* d_ws, size_t ws_size,
                              hipStream_t stream) {
  const float* inputs = (const float*)d_in[0];
  const float* init_h = (const float*)d_in[1];
  const float* sup    = (const float*)d_in[2];
  const float* Wg0 = (const float*)d_in[3];
  const float* bg0 = (const float*)d_in[4];
  const float* Wc0 = (const float*)d_in[5];
  const float* bc0 = (const float*)d_in[6];
  const float* Wg1 = (const float*)d_in[7];
  const float* bg1 = (const float*)d_in[8];
  const float* Wc1 = (const float*)d_in[9];
  const float* bc1 = (const float*)d_in[10];
  float* out = (float*)d_out;
  float* ws  = (float*)d_ws;

  hipMemsetAsync(d_ws, 0, 256, stream);  // zero barrier state
  dcgru_fused<<<GD, NTHR, 0, stream>>>(
      inputs, init_h, sup, Wg0, bg0, Wc0, bc0, Wg1, bg1, Wc1, bc1, out, ws);
}

// Round 4
// 3617.643 us; speedup vs baseline: 4.3971x; 4.3971x over previous
//
#include <hip/hip_runtime.h>
#include <math.h>

// DCGRU encoder — persistent kernel, bf16 MFMA GEMMs, fp32 state/pointwise.
// B=16 T=32 N=128 D=H=128, K=2 (M=3), L=2, 1 support.
// Grid: 256 blocks x 1024 threads (16 waves/CU). Layers pipelined one step
// apart: stage s in [0,33): layer0 computes t=s, layer1 computes t=s-1.
// Phases per stage: P1 diff(h) | P2 gates | P3 diff(rh) | P4 cand+update,
// grid barrier between phases (133 barriers total).

typedef __attribute__((ext_vector_type(8))) short bf16x8;
typedef __attribute__((ext_vector_type(4))) float f32x4;

namespace {
constexpr int GD = 256, NTHR = 1024;
constexpr int CTW = 136;   // catT/D1T row stride in halfwords (128+8: 16B-aligned rows)
constexpr int BFW = 776;   // A-tile row stride in halfwords (768+8: 16B-aligned rows)
}

__device__ __forceinline__ unsigned short f2bf(float x) {
  unsigned u = __float_as_uint(x);
  u += 0x7fff + ((u >> 16) & 1);   // RNE
  return (unsigned short)(u >> 16);
}
__device__ __forceinline__ float bf2f(unsigned hw) {
  return __uint_as_float(hw << 16);
}

// sense-reversing grid barrier (verified in R3 across 8 XCDs)
__device__ __forceinline__ void grid_barrier(unsigned* bar) {
  __syncthreads();
  if (threadIdx.x == 0) {
    unsigned* cnt = bar;
    unsigned* gen = bar + 32;
    unsigned g = __hip_atomic_load(gen, __ATOMIC_RELAXED, __HIP_MEMORY_SCOPE_AGENT);
    unsigned a = __hip_atomic_fetch_add(cnt, 1u, __ATOMIC_ACQ_REL, __HIP_MEMORY_SCOPE_AGENT);
    if (a == (unsigned)(GD - 1)) {
      __hip_atomic_store(cnt, 0u, __ATOMIC_RELAXED, __HIP_MEMORY_SCOPE_AGENT);
      __hip_atomic_fetch_add(gen, 1u, __ATOMIC_ACQ_REL, __HIP_MEMORY_SCOPE_AGENT);
    } else {
      while (__hip_atomic_load(gen, __ATOMIC_ACQUIRE, __HIP_MEMORY_SCOPE_AGENT) == g) {
        __builtin_amdgcn_s_sleep(1);
      }
    }
  }
  __syncthreads();
}

// Diffusion phase: per block = (layer, b, 32-feature slice).
// D1 = S@cat, D2 = 2 S@D1 - cat, via 16x16x32 bf16 MFMA.
// A = S (pre-arranged frags in global), B = catT/D1T (LDS, transposed).
__device__ __forceinline__ void diffusion(
    int bid, int tid, int s, const float* __restrict__ inputs,
    const float* __restrict__ seqs, const float* __restrict__ hsrc_base,
    const unsigned short* __restrict__ Sfr,
    unsigned short* __restrict__ D1g, unsigned short* __restrict__ D2g,
    unsigned short* lds) {
  const int layer = bid >> 7;
  const int t = layer ? (s - 1) : s;
  const bool act = layer ? (s >= 1) : (s < 32);
  if (!act) return;
  const int b = (bid >> 3) & 15, fs = (bid & 7) * 32;
  const int lane = tid & 63, w = tid >> 6, quad = lane >> 4, l16 = lane & 15;
  unsigned short* catT = lds;             // [32][CTW]
  unsigned short* D1T  = lds + 32 * CTW;  // [32][CTW]

  // stage catT[f][n] (bf16, transposed): p -> f = p&31, n2 = (p>>5)*2
  for (int p = tid; p < 2048; p += NTHR) {
    const int f = p & 31, n2 = (p >> 5) << 1;
    float v0, v1;
    if (fs < 128) {
      const float* xb = (layer == 0)
          ? inputs + (long)((b * 32 + t) * 128) * 128
          : seqs + (long)(t & 1) * 262144 + (long)(b * 128) * 128;
      v0 = xb[n2 * 128 + fs + f];
      v1 = xb[(n2 + 1) * 128 + fs + f];
    } else {
      const float* hb = hsrc_base + (long)(layer * 2048 + b * 128) * 128;
      v0 = hb[n2 * 128 + (fs - 128) + f];
      v1 = hb[(n2 + 1) * 128 + (fs - 128) + f];
    }
    *(unsigned*)(catT + f * CTW + n2) =
        (unsigned)f2bf(v0) | ((unsigned)f2bf(v1) << 16);
  }
  __syncthreads();

  // wave = (mt = w>>1, ft = w&1): C tile = D1[mt*16..+15][ft*16..+15] of slice
  const int mt = w >> 1, ft = w & 1;
  const unsigned short* Sb = Sfr + (long)t * 16384;

  f32x4 acc = {0.f, 0.f, 0.f, 0.f};
#pragma unroll
  for (int ks = 0; ks < 4; ks++) {
    bf16x8 a = *(const bf16x8*)(Sb + (((mt * 4 + ks) * 64) + lane) * 8);
    bf16x8 bb = *(const bf16x8*)(catT + (ft * 16 + l16) * CTW + ks * 32 + quad * 8);
    acc = __builtin_amdgcn_mfma_f32_16x16x32_bf16(a, bb, acc, 0, 0, 0);
  }
  // write D1T[f][m] (C layout: col f = l16, rows m = mt*16 + quad*4 + reg)
  {
    unsigned short* dst = D1T + (ft * 16 + l16) * CTW + mt * 16 + quad * 4;
    const unsigned lo = (unsigned)f2bf(acc[0]) | ((unsigned)f2bf(acc[1]) << 16);
    const unsigned hi = (unsigned)f2bf(acc[2]) | ((unsigned)f2bf(acc[3]) << 16);
    *(uint2*)dst = make_uint2(lo, hi);
  }
  __syncthreads();

  f32x4 acc2 = {0.f, 0.f, 0.f, 0.f};
#pragma unroll
  for (int ks = 0; ks < 4; ks++) {
    bf16x8 a = *(const bf16x8*)(Sb + (((mt * 4 + ks) * 64) + lane) * 8);
    bf16x8 bb = *(const bf16x8*)(D1T + (ft * 16 + l16) * CTW + ks * 32 + quad * 8);
    acc2 = __builtin_amdgcn_mfma_f32_16x16x32_bf16(a, bb, acc2, 0, 0, 0);
  }
  // D2 = 2*acc2 - cat; overwrite catT slots (same lane owns read & write)
  {
    unsigned short* cp = catT + (ft * 16 + l16) * CTW + mt * 16 + quad * 4;
    const uint2 cv = *(const uint2*)cp;
    const float d0 = 2.f * acc2[0] - bf2f(cv.x & 0xffffu);
    const float d1 = 2.f * acc2[1] - bf2f(cv.x >> 16);
    const float d2 = 2.f * acc2[2] - bf2f(cv.y & 0xffffu);
    const float d3 = 2.f * acc2[3] - bf2f(cv.y >> 16);
    const unsigned lo = (unsigned)f2bf(d0) | ((unsigned)f2bf(d1) << 16);
    const unsigned hi = (unsigned)f2bf(d2) | ((unsigned)f2bf(d3) << 16);
    *(uint2*)cp = make_uint2(lo, hi);
  }
  __syncthreads();

  // cooperative coalesced global writes: thread = (m = tid>>3, f4 = (tid&7)*4)
  {
    const int m = tid >> 3, f4 = (tid & 7) << 2;
    const long row = (long)(layer * 2048 + b * 128 + m);
    unsigned lo = (unsigned)D1T[(f4 + 0) * CTW + m] |
                  ((unsigned)D1T[(f4 + 1) * CTW + m] << 16);
    unsigned hi = (unsigned)D1T[(f4 + 2) * CTW + m] |
                  ((unsigned)D1T[(f4 + 3) * CTW + m] << 16);
    *(uint2*)(D1g + row * 256 + fs + f4) = make_uint2(lo, hi);
    lo = (unsigned)catT[(f4 + 0) * CTW + m] |
         ((unsigned)catT[(f4 + 1) * CTW + m] << 16);
    hi = (unsigned)catT[(f4 + 2) * CTW + m] |
         ((unsigned)catT[(f4 + 3) * CTW + m] << 16);
    *(uint2*)(D2g + row * 256 + fs + f4) = make_uint2(lo, hi);
  }
}

__global__ void __launch_bounds__(NTHR, 1) dcgru(
    const float* __restrict__ inputs, const float* __restrict__ init_h,
    const float* __restrict__ sup,
    const float* __restrict__ Wg0, const float* __restrict__ bg0,
    const float* __restrict__ Wc0, const float* __restrict__ bc0,
    const float* __restrict__ Wg1, const float* __restrict__ bg1,
    const float* __restrict__ Wc1, const float* __restrict__ bc1,
    float* __restrict__ out, void* __restrict__ wsv) {
  __shared__ unsigned short LDS[16 * BFW];  // 24832 B

  unsigned* bar = (unsigned*)wsv;
  float* h_ws  = (float*)wsv + 64;           // [4096][128]
  float* rh_ws = h_ws + 524288;              // [4096][128]
  float* uu_ws = rh_ws + 524288;             // [4096][128]
  float* seqs  = uu_ws + 524288;             // 2 ping-pong slots x [2048][128]
  unsigned short* D1g = (unsigned short*)(seqs + 524288);  // [4096][256] bf16
  unsigned short* D2g = D1g + 1048576;
  unsigned short* Sfr = D2g + 1048576;       // [32][8mt][4ks][64lane][8] bf16
  unsigned short* Wbg = Sfr + 524288;        // [2][16ot][24ks][64][8]
  unsigned short* Wbc = Wbg + 393216;        // [2][8ot][24ks][64][8]

  const int tid = threadIdx.x, bid = blockIdx.x;
  const int gtid = bid * NTHR + tid, gstride = GD * NTHR;
  const int lane = tid & 63, w = tid >> 6, quad = lane >> 4, l16 = lane & 15;

  // ---- prep: h init + S/W fragment pre-arrangement (bf16) ----
  for (int i = gtid; i < 524288; i += gstride) h_ws[i] = init_h[i];
  for (int idx = gtid; idx < 65536; idx += gstride) {  // S frags
    const int t = idx >> 11, mt = (idx >> 8) & 7, ks = (idx >> 6) & 3, ln = idx & 63;
    const int m = mt * 16 + (ln & 15), k0 = ks * 32 + (ln >> 4) * 8;
    const float* src = sup + (long)t * 16384 + m * 128 + k0;
    bf16x8 v;
#pragma unroll
    for (int j = 0; j < 8; j++) v[j] = (short)f2bf(src[j]);
    *(bf16x8*)(Sfr + (long)idx * 8) = v;
  }
  for (int idx = gtid; idx < 49152; idx += gstride) {  // Wg frags (2x16x24x64)
    const int l = idx / 24576;
    int rem = idx - l * 24576;
    const int ot = rem / 1536; rem -= ot * 1536;
    const int ks = rem >> 6, ln = rem & 63;
    const int o = ot * 16 + (ln & 15);
    const float* W = l ? Wg1 : Wg0;
    bf16x8 v;
#pragma unroll
    for (int j = 0; j < 8; j++) {
      const int kk = ks * 32 + (ln >> 4) * 8 + j;
      const int mm = kk >> 8, d = kk & 255;   // row reorder (d*3+mm) -> k
      v[j] = (short)f2bf(W[(d * 3 + mm) * 256 + o]);
    }
    *(bf16x8*)(Wbg + (long)idx * 8) = v;
  }
  for (int idx = gtid; idx < 24576; idx += gstride) {  // Wc frags (2x8x24x64)
    const int l = idx / 12288;
    int rem = idx - l * 12288;
    const int ot = rem / 1536; rem -= ot * 1536;
    const int ks = rem >> 6, ln = rem & 63;
    const int o = ot * 16 + (ln & 15);
    const float* W = l ? Wc1 : Wc0;
    bf16x8 v;
#pragma unroll
    for (int j = 0; j < 8; j++) {
      const int kk = ks * 32 + (ln >> 4) * 8 + j;
      const int mm = kk >> 8, d = kk & 255;
      v[j] = (short)f2bf(W[(d * 3 + mm) * 128 + o]);
    }
    *(bf16x8*)(Wbc + (long)idx * 8) = v;
  }
  grid_barrier(bar);

  // ---- main pipelined loop ----
  for (int s = 0; s < 33; s++) {
    // P1: diffusion on h
    diffusion(bid, tid, s, inputs, seqs, h_ws, Sfr, D1g, D2g, LDS);
    grid_barrier(bar);

    // P2: gates GEMM [16 rows x 256 outs per block]
    {
      const int row0 = bid * 16;
      const int layer = row0 >> 11;
      const int t = layer ? (s - 1) : s;
      const bool act = layer ? (s >= 1) : (s < 32);
      if (act) {
        for (int p = tid; p < 6144; p += NTHR) {  // stage A tile (bf16 pairs)
          const int rr = p / 384, k2 = (p - rr * 384) << 1;
          const int row = row0 + rr, r2 = row & 2047, b = r2 >> 7, n = r2 & 127;
          unsigned pk;
          if (k2 < 256) {
            float2 v;
            if (k2 < 128) {
              v = (layer == 0)
                  ? *(const float2*)&inputs[(long)((b * 32 + t) * 128 + n) * 128 + k2]
                  : *(const float2*)&seqs[(long)(t & 1) * 262144 + (long)r2 * 128 + k2];
            } else {
              v = *(const float2*)&h_ws[(long)row * 128 + (k2 - 128)];
            }
            pk = (unsigned)f2bf(v.x) | ((unsigned)f2bf(v.y) << 16);
          } else if (k2 < 512) {
            pk = *(const unsigned*)(D1g + (long)row * 256 + (k2 - 256));
          } else {
            pk = *(const unsigned*)(D2g + (long)row * 256 + (k2 - 512));
          }
          *(unsigned*)(LDS + rr * BFW + k2) = pk;
        }
        __syncthreads();
        f32x4 acc = {0.f, 0.f, 0.f, 0.f};
        const unsigned short* Wb = Wbg + ((long)(layer * 16 + w) * 24) * 512;
        for (int ks = 0; ks < 24; ks++) {
          bf16x8 a = *(const bf16x8*)(LDS + l16 * BFW + ks * 32 + quad * 8);
          bf16x8 bb = *(const bf16x8*)(Wb + ks * 512 + lane * 8);
          acc = __builtin_amdgcn_mfma_f32_16x16x32_bf16(a, bb, acc, 0, 0, 0);
        }
        const int o = w * 16 + l16;
        const float bias = (layer ? bg1 : bg0)[o];
#pragma unroll
        for (int r = 0; r < 4; r++) {
          const int row = row0 + quad * 4 + r;
          const float g = 1.f / (1.f + __expf(-(acc[r] + bias)));
          if (o < 128) rh_ws[(long)row * 128 + o] = g * h_ws[(long)row * 128 + o];
          else         uu_ws[(long)row * 128 + (o - 128)] = g;
        }
      }
    }
    grid_barrier(bar);

    // P3: diffusion on rh
    diffusion(bid, tid, s, inputs, seqs, rh_ws, Sfr, D1g, D2g, LDS);
    grid_barrier(bar);

    // P4: candidate GEMM [16 rows x 128 outs] + GRU update
    {
      const int row0 = bid * 16;
      const int layer = row0 >> 11;
      const int t = layer ? (s - 1) : s;
      const bool act = layer ? (s >= 1) : (s < 32);
      if (act) {
        for (int p = tid; p < 6144; p += NTHR) {
          const int rr = p / 384, k2 = (p - rr * 384) << 1;
          const int row = row0 + rr, r2 = row & 2047, b = r2 >> 7, n = r2 & 127;
          unsigned pk;
          if (k2 < 256) {
            float2 v;
            if (k2 < 128) {
              v = (layer == 0)
                  ? *(const float2*)&inputs[(long)((b * 32 + t) * 128 + n) * 128 + k2]
                  : *(const float2*)&seqs[(long)(t & 1) * 262144 + (long)r2 * 128 + k2];
            } else {
              v = *(const float2*)&rh_ws[(long)row * 128 + (k2 - 128)];
            }
            pk = (unsigned)f2bf(v.x) | ((unsigned)f2bf(v.y) << 16);
          } else if (k2 < 512) {
            pk = *(const unsigned*)(D1g + (long)row * 256 + (k2 - 256));
          } else {
            pk = *(const unsigned*)(D2g + (long)row * 256 + (k2 - 512));
          }
          *(unsigned*)(LDS + rr * BFW + k2) = pk;
        }
        __syncthreads();
        if (w < 8) {
          f32x4 acc = {0.f, 0.f, 0.f, 0.f};
          const unsigned short* Wb = Wbc + ((long)(layer * 8 + w) * 24) * 512;
          for (int ks = 0; ks < 24; ks++) {
            bf16x8 a = *(const bf16x8*)(LDS + l16 * BFW + ks * 32 + quad * 8);
            bf16x8 bb = *(const bf16x8*)(Wb + ks * 512 + lane * 8);
            acc = __builtin_amdgcn_mfma_f32_16x16x32_bf16(a, bb, acc, 0, 0, 0);
          }
          const int o = w * 16 + l16;
          const float bias = (layer ? bc1 : bc0)[o];
#pragma unroll
          for (int r = 0; r < 4; r++) {
            const int row = row0 + quad * 4 + r, r2 = row & 2047;
            const float cv = tanhf(acc[r] + bias);
            const float uv = uu_ws[(long)row * 128 + o];
            const float hv = h_ws[(long)row * 128 + o];
            const float hn = uv * hv + (1.f - uv) * cv;
            h_ws[(long)row * 128 + o] = hn;
            if (layer == 0) {
              seqs[(long)(s & 1) * 262144 + (long)r2 * 128 + o] = hn;
              if (t == 31) out[(long)r2 * 128 + o] = hn;
            } else {
              out[524288 + (long)t * 262144 + (long)r2 * 128 + o] = hn;
              if (t == 31) out[262144 + (long)r2 * 128 + o] = hn;
            }
          }
        }
      }
    }
    grid_barrier(bar);
  }
}

extern "C" void kernel_launch(void* const* d_in, const int* in_sizes, int n_in,
                              void* d_out, int out_size, void* d_ws, size_t ws_size,
                              hipStream_t stream) {
  const float* inputs = (const float*)d_in[0];
  const float* init_h = (const float*)d_in[1];
  const float* sup    = (const float*)d_in[2];
  const float* Wg0 = (const float*)d_in[3];
  const float* bg0 = (const float*)d_in[4];
  const float* Wc0 = (const float*)d_in[5];
  const float* bc0 = (const float*)d_in[6];
  const float* Wg1 = (const float*)d_in[7];
  const float* bg1 = (const float*)d_in[8];
  const float* Wc1 = (const float*)d_in[9];
  const float* bc1 = (const float*)d_in[10];
  float* out = (float*)d_out;

  hipMemsetAsync(d_ws, 0, 256, stream);  // zero barrier state
  dcgru<<<GD, NTHR, 0, stream>>>(inputs, init_h, sup, Wg0, bg0, Wc0, bc0,
                                 Wg1, bg1, Wc1, bc1, out, d_ws);
}